// Round 8
// baseline (518.797 us; speedup 1.0000x reference)
//
#include <hip/hip_runtime.h>
#include <hip/hip_bf16.h>

#define N_NODES 170000
#define N_EDGES 1200000

// ---- coarse/fine counting sort geometry ----
#define AITEMS 2048              // edges per coarse block
#define NB_A   586               // ceil(E / AITEMS)
#define NCB    333               // coarse buckets = ceil(N / 512), key = dst>>9
#define SCAN_A_N      (NCB * NB_A)        // 195138 counters
#define SCAN_A_BLOCKS 191                 // ceil(SCAN_A_N / 1024)
#define SCAN_A_PAD    (SCAN_A_BLOCKS * 1024)
#define HISTA_PAD     195140              // SCAN_A_N padded to 16B

// ---- deg_out packed-LDS histogram geometry (round-4 occupancy lesson) ----
#define DOUT_NPC    16384        // nodes per chunk (packed 2/word = 32KB)
#define DOUT_WPC    8192         // words per chunk
#define DOUT_NCHUNK 11           // ceil(N / DOUT_NPC)
#define DOUT_NSLICE 96           // E/96 = 12500 exactly
#define DOUT_SLICE_E (N_EDGES / DOUT_NSLICE)
#define WORDS_N     85000        // N/2 words over all nodes

typedef short bf16x8 __attribute__((ext_vector_type(8)));
typedef float f32x4 __attribute__((ext_vector_type(4)));

__device__ __forceinline__ void bf_split(float v, __hip_bfloat16& h, __hip_bfloat16& l)
{
    h = __float2bfloat16(v);
    l = __float2bfloat16(v - __bfloat162float(h));
}

// Swizzled LDS byte address for a [32][128] bf16 plane (256B row stride).
__device__ __forceinline__ int lds_addr(int row, int col)
{
    return (row * 256 + col * 2) ^ ((row & 7) << 4);
}

// =====================================================================
// CSR build, zero global atomics (round-2 lesson: atomic scope does not
// change memory-side RMW routing on gfx950). Deterministic two-phase
// counting sort with LDS atomics + exclusively-owned global slots.
// =====================================================================

__global__ __launch_bounds__(256) void coarse_hist_kernel(
    const int* __restrict__ dst, int* __restrict__ histA, int nedges)
{
    __shared__ int h[NCB];
    int t = threadIdx.x;
    for (int j = t; j < NCB; j += 256) h[j] = 0;
    __syncthreads();
    int base = blockIdx.x * AITEMS;
    #pragma unroll
    for (int j = 0; j < AITEMS / 256; j++) {
        int i = base + j * 256 + t;
        if (i < nedges) atomicAdd(&h[dst[i] >> 9], 1);   // LDS atomic
    }
    __syncthreads();
    for (int j = t; j < NCB; j += 256)
        histA[j * NB_A + blockIdx.x] = h[j];
}

__global__ __launch_bounds__(256) void scan1_kernel(
    const int* __restrict__ in, int* __restrict__ partial,
    int* __restrict__ blockSums, int n)
{
    __shared__ int sdata[256];
    int t = threadIdx.x;
    int base = blockIdx.x * 1024 + t * 4;
    int4 v = make_int4(0, 0, 0, 0);
    if (base + 3 < n) v = *(const int4*)&in[base];
    else {
        if (base + 0 < n) v.x = in[base + 0];
        if (base + 1 < n) v.y = in[base + 1];
        if (base + 2 < n) v.z = in[base + 2];
        if (base + 3 < n) v.w = in[base + 3];
    }
    int tsum = v.x + v.y + v.z + v.w;
    sdata[t] = tsum;
    __syncthreads();
    for (int off = 1; off < 256; off <<= 1) {
        int add = 0;
        if (t >= off) add = sdata[t - off];
        __syncthreads();
        if (t >= off) sdata[t] += add;
        __syncthreads();
    }
    int excl = sdata[t] - tsum;
    int4 o;
    o.x = excl;
    o.y = o.x + v.x;
    o.z = o.y + v.y;
    o.w = o.z + v.z;
    *(int4*)&partial[base] = o;
    if (t == 255) blockSums[blockIdx.x] = sdata[255];
}

__global__ __launch_bounds__(256) void scan2_kernel(int* __restrict__ blockSums, int nb)
{
    __shared__ int sdata[256];
    int t = threadIdx.x;
    int val = (t < nb) ? blockSums[t] : 0;
    sdata[t] = val;
    __syncthreads();
    for (int off = 1; off < 256; off <<= 1) {
        int add = 0;
        if (t >= off) add = sdata[t - off];
        __syncthreads();
        if (t >= off) sdata[t] += add;
        __syncthreads();
    }
    if (t < nb) blockSums[t] = sdata[t] - val;   // exclusive
}

__global__ __launch_bounds__(256) void scan3_kernel(
    int* __restrict__ buf, const int* __restrict__ blockSums)
{
    int off = blockSums[blockIdx.x];
    int base = blockIdx.x * 1024 + threadIdx.x * 4;
    int4 v = *(const int4*)&buf[base];
    v.x += off; v.y += off; v.z += off; v.w += off;
    *(int4*)&buf[base] = v;
}

__global__ __launch_bounds__(256) void coarse_scatter_kernel(
    const int* __restrict__ src, const int* __restrict__ dst,
    const int* __restrict__ scanA, int* __restrict__ pairs, int nedges)
{
    __shared__ int base[NCB];
    __shared__ int cur[NCB];
    int t = threadIdx.x;
    for (int j = t; j < NCB; j += 256) {
        base[j] = scanA[j * NB_A + blockIdx.x];
        cur[j] = 0;
    }
    __syncthreads();
    int eb = blockIdx.x * AITEMS;
    #pragma unroll
    for (int j = 0; j < AITEMS / 256; j++) {
        int i = eb + j * 256 + t;
        if (i < nedges) {
            int d = dst[i];
            int cb = d >> 9;
            int r = atomicAdd(&cur[cb], 1);          // LDS atomic-return
            pairs[base[cb] + r] = (src[i] << 9) | (d & 511);
        }
    }
}

__global__ __launch_bounds__(256) void bucket_sort_kernel(
    const int* __restrict__ pairs, const int* __restrict__ scanA,
    int* __restrict__ csr, int* __restrict__ row_start,
    float* __restrict__ norm_in, int nedges)
{
    __shared__ int hist[512];
    __shared__ int curs[512];
    __shared__ int sdata[256];
    int cb = blockIdx.x;
    int t = threadIdx.x;
    int beg = scanA[cb * NB_A];
    int end = (cb == NCB - 1) ? nedges : scanA[(cb + 1) * NB_A];

    hist[t] = 0; hist[t + 256] = 0;
    __syncthreads();
    for (int j = beg + t; j < end; j += 256)
        atomicAdd(&hist[pairs[j] & 511], 1);
    __syncthreads();

    int a = hist[2 * t], b = hist[2 * t + 1];
    sdata[t] = a + b;
    __syncthreads();
    for (int off = 1; off < 256; off <<= 1) {
        int add = 0;
        if (t >= off) add = sdata[t - off];
        __syncthreads();
        if (t >= off) sdata[t] += add;
        __syncthreads();
    }
    int epair = sdata[t] - (a + b);
    curs[2 * t]     = beg + epair;
    curs[2 * t + 1] = beg + epair + a;
    __syncthreads();

    int nodeBase = cb << 9;
    for (int s = t; s < 512; s += 256) {
        int v = nodeBase + s;
        if (v < N_NODES) {
            row_start[v] = curs[s];
            norm_in[v] = rsqrtf(fmaxf((float)hist[s], 1.0f));
        }
    }
    if (cb == NCB - 1 && t == 0) row_start[N_NODES] = nedges;
    __syncthreads();

    for (int j = beg + t; j < end; j += 256) {
        int p = pairs[j];
        int pos = atomicAdd(&curs[p & 511], 1);      // LDS atomic-return
        csr[pos] = p >> 9;
    }
}

__global__ __launch_bounds__(256) void degout_hist_kernel(
    const int* __restrict__ src, unsigned* __restrict__ partial)
{
    __shared__ unsigned h[DOUT_WPC];
    int chunk = blockIdx.x / DOUT_NSLICE;
    int slice = blockIdx.x % DOUT_NSLICE;
    int lo = chunk * DOUT_NPC;
    int t = threadIdx.x;
    #pragma unroll
    for (int j = 0; j < DOUT_WPC / 256; j++) h[j * 256 + t] = 0;
    __syncthreads();
    const int4* sp = (const int4*)(src + slice * DOUT_SLICE_E);
    for (int i = t; i < DOUT_SLICE_E / 4; i += 256) {
        int4 v = sp[i];
        unsigned a = (unsigned)(v.x - lo);
        if (a < DOUT_NPC) atomicAdd(&h[a >> 1], 1u << ((a & 1) * 16));
        a = (unsigned)(v.y - lo);
        if (a < DOUT_NPC) atomicAdd(&h[a >> 1], 1u << ((a & 1) * 16));
        a = (unsigned)(v.z - lo);
        if (a < DOUT_NPC) atomicAdd(&h[a >> 1], 1u << ((a & 1) * 16));
        a = (unsigned)(v.w - lo);
        if (a < DOUT_NPC) atomicAdd(&h[a >> 1], 1u << ((a & 1) * 16));
    }
    __syncthreads();
    int wlo = chunk * DOUT_WPC;
    int nw = min(DOUT_WPC, WORDS_N - wlo);
    for (int j = t; j < nw; j += 256)
        partial[(size_t)slice * WORDS_N + wlo + j] = h[j];
}

__global__ __launch_bounds__(256) void degout_combine_kernel(
    const unsigned* __restrict__ partial, float* __restrict__ norm_out)
{
    int w = blockIdx.x * 256 + threadIdx.x;
    if (w >= WORDS_N) return;
    unsigned slo = 0, shi = 0;
    #pragma unroll
    for (int s = 0; s < DOUT_NSLICE; s++) {
        unsigned x = partial[(size_t)s * WORDS_N + w];
        slo += x & 0xFFFFu;
        shi += x >> 16;
    }
    norm_out[2 * w]     = rsqrtf(fmaxf((float)slo, 1.0f));
    norm_out[2 * w + 1] = rsqrtf(fmaxf((float)shi, 1.0f));
}

// ---------------- fp32 -> bf16 row cast (feat) ----------------
__global__ __launch_bounds__(256) void f2bf_kernel(
    const float* __restrict__ in, __hip_bfloat16* __restrict__ outp, int n8)
{
    int i = blockIdx.x * 256 + threadIdx.x;
    if (i >= n8) return;
    float4 a = *(const float4*)&in[(size_t)i * 8];
    float4 b = *(const float4*)&in[(size_t)i * 8 + 4];
    float4 packed;
    __hip_bfloat162* p = (__hip_bfloat162*)&packed;
    p[0].x = __float2bfloat16(a.x); p[0].y = __float2bfloat16(a.y);
    p[1].x = __float2bfloat16(a.z); p[1].y = __float2bfloat16(a.w);
    p[2].x = __float2bfloat16(b.x); p[2].y = __float2bfloat16(b.y);
    p[3].x = __float2bfloat16(b.z); p[3].y = __float2bfloat16(b.w);
    *(float4*)&outp[(size_t)i * 8] = packed;
}

// ---------------- W (K x Nout fp32) -> transposed split planes Wt[n][k] bf16 ----
__global__ __launch_bounds__(256) void wsplit_kernel(
    const float* __restrict__ W, int nout,
    __hip_bfloat16* __restrict__ Whi, __hip_bfloat16* __restrict__ Wlo)
{
    int i = blockIdx.x * 256 + threadIdx.x;   // over 128*nout
    if (i >= 128 * nout) return;
    int k = i / nout, n = i - k * nout;
    float v = W[i];
    __hip_bfloat16 h, l;
    bf_split(v, h, l);
    Whi[n * 128 + k] = h;
    Wlo[n * 128 + k] = l;
}

// =====================================================================
// Fused GCN layer (round-6 structure) + round-7 change: register-batched
// gather. The old inner loop (runtime trip count) kept ~1 outstanding
// 256B row-load per 16-lane group -> latency-bound (133us, MfmaUtil 7.5%,
// VALUBusy 27%, HBM 22%, nothing saturated). New form: fixed-trip,
// fully-unrolled batches of 8 independent row loads into registers
// (one waitcnt per 8 rows), weight-masked pad lanes (dup row id -> L1
// hit, weight 0 -> exact zero contribution; bitwise-identical numerics).
// =====================================================================
template<bool SCALE_SRC, bool FUSE2>
__global__ __launch_bounds__(256) void fused_layer_kernel(
    const __hip_bfloat16* __restrict__ hin, const int* __restrict__ csr,
    const int* __restrict__ row_start, const float* __restrict__ norm_out,
    const float* __restrict__ norm_in, const __hip_bfloat16* __restrict__ Wthi,
    const __hip_bfloat16* __restrict__ Wtlo, const float* __restrict__ bias,
    const float* __restrict__ rowscale, const __hip_bfloat16* __restrict__ W2thi,
    const __hip_bfloat16* __restrict__ W2tlo, __hip_bfloat16* __restrict__ outp)
{
    __shared__ __align__(16) unsigned char smem[16384];   // hi @0, lo @8192
    const int r0 = blockIdx.x * 32;

    // ---- phase 1: gather 32 rows (16 groups x 2 rows, 16 lanes/row) ----
    {
        const int g = threadIdx.x >> 4;
        const int l = threadIdx.x & 15;
        const int gbase = threadIdx.x & 48;
        for (int rr = 0; rr < 2; rr++) {
            const int lrow = g + rr * 16;
            const int row = r0 + lrow;
            float acc[8] = {};
            if (row < N_NODES) {
                int beg = row_start[row];
                int end = row_start[row + 1];
                for (int j = beg; j < end; j += 16) {
                    int cnt = min(16, end - j);
                    int sv = 0;
                    float wv = 0.f;
                    if (j + l < end) {
                        sv = csr[j + l];
                        wv = SCALE_SRC ? norm_out[sv] : 1.f;
                    }
                    int s0 = __shfl(sv, gbase);      // first edge: always valid
                    if (j + l >= end) sv = s0;       // pad -> dup row, weight 0
                    #pragma unroll
                    for (int ib = 0; ib < 16; ib += 8) {
                        if (ib < cnt) {
                            float4 rg[8];
                            float ww[8];
                            #pragma unroll
                            for (int k = 0; k < 8; k++) {
                                int s = __shfl(sv, gbase + ib + k);
                                ww[k] = __shfl(wv, gbase + ib + k);
                                rg[k] = *(const float4*)(hin + (size_t)s * 128 + l * 8);
                            }
                            #pragma unroll
                            for (int k = 0; k < 8; k++) {
                                const __hip_bfloat162* pp = (const __hip_bfloat162*)&rg[k];
                                float sc = ww[k];
                                float2 f0 = __bfloat1622float2(pp[0]);
                                float2 f1 = __bfloat1622float2(pp[1]);
                                float2 f2 = __bfloat1622float2(pp[2]);
                                float2 f3 = __bfloat1622float2(pp[3]);
                                acc[0] += f0.x * sc; acc[1] += f0.y * sc;
                                acc[2] += f1.x * sc; acc[3] += f1.y * sc;
                                acc[4] += f2.x * sc; acc[5] += f2.y * sc;
                                acc[6] += f3.x * sc; acc[7] += f3.y * sc;
                            }
                        }
                    }
                }
            }
            float ni = (row < N_NODES) ? norm_in[row] : 0.f;  // invalid rows -> zeros
            float4 ph, pl;
            __hip_bfloat16* hp = (__hip_bfloat16*)&ph;
            __hip_bfloat16* lp = (__hip_bfloat16*)&pl;
            #pragma unroll
            for (int jj = 0; jj < 8; jj++) bf_split(acc[jj] * ni, hp[jj], lp[jj]);
            int off = lds_addr(lrow, l * 8);
            *(float4*)(smem + off) = ph;
            *(float4*)(smem + 8192 + off) = pl;
        }
    }
    __syncthreads();

    // ---- phase 2: GEMM1 (128 cols; wave w owns col-tiles 2w, 2w+1) ----
    const int wave = threadIdx.x >> 6;
    const int lane = threadIdx.x & 63;
    const int n = lane & 15;
    const int q = lane >> 4;
    const size_t bbase = (size_t)n * 128 + q * 8;
    const f32x4 zero = {0.f, 0.f, 0.f, 0.f};
    f32x4 acc0[2], acc1[2];
    acc0[0] = zero; acc0[1] = zero; acc1[0] = zero; acc1[1] = zero;

    #pragma unroll 1
    for (int kc = 0; kc < 4; kc++) {
        const int a0 = lds_addr(n, q * 8 + kc * 32);
        const int a1 = lds_addr(n + 16, q * 8 + kc * 32);
        bf16x8 ah0 = *(const bf16x8*)(smem + a0);
        bf16x8 al0 = *(const bf16x8*)(smem + 8192 + a0);
        bf16x8 ah1 = *(const bf16x8*)(smem + a1);
        bf16x8 al1 = *(const bf16x8*)(smem + 8192 + a1);
        #pragma unroll
        for (int c = 0; c < 2; c++) {
            const int ct = wave * 2 + c;
            bf16x8 bh = *(const bf16x8*)(Wthi + (size_t)ct * 2048 + bbase + kc * 32);
            bf16x8 bl = *(const bf16x8*)(Wtlo + (size_t)ct * 2048 + bbase + kc * 32);
            acc0[c] = __builtin_amdgcn_mfma_f32_16x16x32_bf16(ah0, bh, acc0[c], 0, 0, 0);
            acc0[c] = __builtin_amdgcn_mfma_f32_16x16x32_bf16(al0, bh, acc0[c], 0, 0, 0);
            acc0[c] = __builtin_amdgcn_mfma_f32_16x16x32_bf16(ah0, bl, acc0[c], 0, 0, 0);
            acc1[c] = __builtin_amdgcn_mfma_f32_16x16x32_bf16(ah1, bh, acc1[c], 0, 0, 0);
            acc1[c] = __builtin_amdgcn_mfma_f32_16x16x32_bf16(al1, bh, acc1[c], 0, 0, 0);
            acc1[c] = __builtin_amdgcn_mfma_f32_16x16x32_bf16(ah1, bl, acc1[c], 0, 0, 0);
        }
    }

    float bcol[2];
    bcol[0] = bias[(wave * 2 + 0) * 16 + n];
    bcol[1] = bias[(wave * 2 + 1) * 16 + n];

    if (!FUSE2) {
        #pragma unroll
        for (int r = 0; r < 4; r++) {
            int g0 = r0 + q * 4 + r;
            int g1 = g0 + 16;
            float rs0 = rowscale[min(g0, N_NODES - 1)];
            float rs1 = rowscale[min(g1, N_NODES - 1)];
            #pragma unroll
            for (int c = 0; c < 2; c++) {
                int col = (wave * 2 + c) * 16 + n;
                float v0 = fmaxf(acc0[c][r] + bcol[c], 0.f) * rs0;
                float v1 = fmaxf(acc1[c][r] + bcol[c], 0.f) * rs1;
                if (g0 < N_NODES) outp[(size_t)g0 * 128 + col] = __float2bfloat16(v0);
                if (g1 < N_NODES) outp[(size_t)g1 * 128 + col] = __float2bfloat16(v1);
            }
        }
    } else {
        // stage h2' = relu(acc+b)*rowscale back into LDS (split), then GEMM2.
        __syncthreads();   // all waves done reading A planes
        #pragma unroll
        for (int r = 0; r < 4; r++) {
            int lr0 = q * 4 + r;
            int lr1 = lr0 + 16;
            float rs0 = rowscale[min(r0 + lr0, N_NODES - 1)];
            float rs1 = rowscale[min(r0 + lr1, N_NODES - 1)];
            #pragma unroll
            for (int c = 0; c < 2; c++) {
                int col = (wave * 2 + c) * 16 + n;
                float v0 = fmaxf(acc0[c][r] + bcol[c], 0.f) * rs0;
                float v1 = fmaxf(acc1[c][r] + bcol[c], 0.f) * rs1;
                __hip_bfloat16 hh, ll;
                bf_split(v0, hh, ll);
                *(__hip_bfloat16*)(smem + lds_addr(lr0, col)) = hh;
                *(__hip_bfloat16*)(smem + 8192 + lds_addr(lr0, col)) = ll;
                bf_split(v1, hh, ll);
                *(__hip_bfloat16*)(smem + lds_addr(lr1, col)) = hh;
                *(__hip_bfloat16*)(smem + 8192 + lds_addr(lr1, col)) = ll;
            }
        }
        __syncthreads();

        // GEMM2: 64 output cols; wave w owns col-tile w.
        f32x4 c0 = zero, c1 = zero;
        #pragma unroll 1
        for (int kc = 0; kc < 4; kc++) {
            const int a0 = lds_addr(n, q * 8 + kc * 32);
            const int a1 = lds_addr(n + 16, q * 8 + kc * 32);
            bf16x8 ah0 = *(const bf16x8*)(smem + a0);
            bf16x8 al0 = *(const bf16x8*)(smem + 8192 + a0);
            bf16x8 ah1 = *(const bf16x8*)(smem + a1);
            bf16x8 al1 = *(const bf16x8*)(smem + 8192 + a1);
            bf16x8 bh = *(const bf16x8*)(W2thi + (size_t)wave * 2048 + bbase + kc * 32);
            bf16x8 bl = *(const bf16x8*)(W2tlo + (size_t)wave * 2048 + bbase + kc * 32);
            c0 = __builtin_amdgcn_mfma_f32_16x16x32_bf16(ah0, bh, c0, 0, 0, 0);
            c0 = __builtin_amdgcn_mfma_f32_16x16x32_bf16(al0, bh, c0, 0, 0, 0);
            c0 = __builtin_amdgcn_mfma_f32_16x16x32_bf16(ah0, bl, c0, 0, 0, 0);
            c1 = __builtin_amdgcn_mfma_f32_16x16x32_bf16(ah1, bh, c1, 0, 0, 0);
            c1 = __builtin_amdgcn_mfma_f32_16x16x32_bf16(al1, bh, c1, 0, 0, 0);
            c1 = __builtin_amdgcn_mfma_f32_16x16x32_bf16(ah1, bl, c1, 0, 0, 0);
        }
        #pragma unroll
        for (int r = 0; r < 4; r++) {
            int g0 = r0 + q * 4 + r;
            int g1 = g0 + 16;
            int col = wave * 16 + n;
            if (g0 < N_NODES) outp[(size_t)g0 * 64 + col] = __float2bfloat16(c0[r]);
            if (g1 < N_NODES) outp[(size_t)g1 * 64 + col] = __float2bfloat16(c1[r]);
        }
    }
}

// ---------------- final pull aggregation (W=64): out = agg(tbf)*ni + b2 ----
// Same register-batched load restructure as the fused gather.
__global__ __launch_bounds__(256) void final_gather_kernel(
    const __hip_bfloat16* __restrict__ h, const int* __restrict__ csr,
    const int* __restrict__ row_start, const float* __restrict__ norm_in,
    const float* __restrict__ bias, float* __restrict__ outf)
{
    int tid = blockIdx.x * 256 + threadIdx.x;
    int row = tid >> 4;                 // 16 lanes per row
    int l = threadIdx.x & 15;
    int gbase = threadIdx.x & 48;
    if (row >= N_NODES) return;
    int beg = row_start[row];
    int end = row_start[row + 1];
    float acc[4] = {};
    for (int j = beg; j < end; j += 16) {
        int cnt = min(16, end - j);
        int sv = 0;
        float wv = 0.f;
        if (j + l < end) { sv = csr[j + l]; wv = 1.f; }
        int s0 = __shfl(sv, gbase);
        if (j + l >= end) sv = s0;
        #pragma unroll
        for (int ib = 0; ib < 16; ib += 8) {
            if (ib < cnt) {
                float2 rg[8];
                float ww[8];
                #pragma unroll
                for (int k = 0; k < 8; k++) {
                    int s = __shfl(sv, gbase + ib + k);
                    ww[k] = __shfl(wv, gbase + ib + k);
                    rg[k] = *(const float2*)(h + (size_t)s * 64 + l * 4);
                }
                #pragma unroll
                for (int k = 0; k < 8; k++) {
                    const __hip_bfloat162* pp = (const __hip_bfloat162*)&rg[k];
                    float sc = ww[k];
                    float2 f0 = __bfloat1622float2(pp[0]);
                    float2 f1 = __bfloat1622float2(pp[1]);
                    acc[0] += f0.x * sc; acc[1] += f0.y * sc;
                    acc[2] += f1.x * sc; acc[3] += f1.y * sc;
                }
            }
        }
    }
    float ni = norm_in[row];
    float4 o0 = make_float4(acc[0] * ni, acc[1] * ni, acc[2] * ni, acc[3] * ni);
    float4 b = *(const float4*)&bias[l * 4];
    o0.x += b.x; o0.y += b.y; o0.z += b.z; o0.w += b.w;
    *(float4*)&outf[(size_t)row * 64 + l * 4] = o0;
}

extern "C" void kernel_launch(void* const* d_in, const int* in_sizes, int n_in,
                              void* d_out, int out_size, void* d_ws, size_t ws_size,
                              hipStream_t stream)
{
    const float* feat = (const float*)d_in[0];
    const int* src    = (const int*)d_in[1];
    const int* dst    = (const int*)d_in[2];
    const float* W0   = (const float*)d_in[3];
    const float* b0   = (const float*)d_in[4];
    const float* W1   = (const float*)d_in[5];
    const float* b1   = (const float*)d_in[6];
    const float* W2   = (const float*)d_in[7];
    const float* b2   = (const float*)d_in[8];
    float* out = (float*)d_out;

    const int N = N_NODES;
    const int E = N_EDGES;

    // ---- workspace layout ----
    char* ws = (char*)d_ws;
    float* norm_out = (float*)ws;                    // N
    float* norm_in  = norm_out + N;                  // N
    int* row_start  = (int*)(norm_in + N);           // N+1 (padded to 170004)
    int* csr        = row_start + 170004;            // E
    __hip_bfloat16* Wt0hi = (__hip_bfloat16*)(csr + E);   // 16384 each
    __hip_bfloat16* Wt0lo = Wt0hi + 16384;
    __hip_bfloat16* Wt1hi = Wt0lo + 16384;
    __hip_bfloat16* Wt1lo = Wt1hi + 16384;
    __hip_bfloat16* Wt2hi = Wt1lo + 16384;           // 8192 each
    __hip_bfloat16* Wt2lo = Wt2hi + 8192;
    __hip_bfloat16* bfbuf = Wt2lo + 8192;            // N*128 (featbf, then tbf)
    __hip_bfloat16* h1    = bfbuf + (size_t)N * 128; // N*128 (layer-1 output)
    __hip_bfloat16* aux   = h1 + (size_t)N * 128;    // N*128 (build scratch only)
    // CSR-build scratch aliases h1/aux (dead until fused1 writes h1, which
    // runs strictly after the build in stream order):
    //   histA + scanA + blockSums + partial(32.6MB) -> on h1 (43.5MB)
    //   pairs (int[E], 4.8MB)                       -> on aux
    int* histA          = (int*)h1;                  // HISTA_PAD
    int* scanA          = histA + HISTA_PAD;         // SCAN_A_PAD + 4
    int* blockSumsA     = scanA + SCAN_A_PAD + 4;    // 256
    unsigned* partial   = (unsigned*)(blockSumsA + 256);  // DOUT_NSLICE * WORDS_N
    int* pairs          = (int*)aux;                 // E

    // ---- CSR + norms build (no global atomics) ----
    degout_hist_kernel<<<DOUT_NCHUNK * DOUT_NSLICE, 256, 0, stream>>>(src, partial);
    degout_combine_kernel<<<(WORDS_N + 255) / 256, 256, 0, stream>>>(partial, norm_out);
    coarse_hist_kernel<<<NB_A, 256, 0, stream>>>(dst, histA, E);
    scan1_kernel<<<SCAN_A_BLOCKS, 256, 0, stream>>>(histA, scanA, blockSumsA, SCAN_A_N);
    scan2_kernel<<<1, 256, 0, stream>>>(blockSumsA, SCAN_A_BLOCKS);
    scan3_kernel<<<SCAN_A_BLOCKS, 256, 0, stream>>>(scanA, blockSumsA);
    coarse_scatter_kernel<<<NB_A, 256, 0, stream>>>(src, dst, scanA, pairs, E);
    bucket_sort_kernel<<<NCB, 256, 0, stream>>>(pairs, scanA, csr, row_start, norm_in, E);
    f2bf_kernel<<<(N * 16 + 255) / 256, 256, 0, stream>>>(feat, bfbuf, N * 16);
    wsplit_kernel<<<64, 256, 0, stream>>>(W0, 128, Wt0hi, Wt0lo);
    wsplit_kernel<<<64, 256, 0, stream>>>(W1, 128, Wt1hi, Wt1lo);
    wsplit_kernel<<<32, 256, 0, stream>>>(W2, 64, Wt2hi, Wt2lo);

    const int fusedBlocks = (N + 31) / 32;           // 5313
    const int gatherBlocks = (N * 16 + 255) / 256;

    // ---- Layer 1 (fused): h1 = relu(agg(featbf*no)*ni @ W0 + b0) * no
    fused_layer_kernel<true, false><<<fusedBlocks, 256, 0, stream>>>(
        bfbuf, csr, row_start, norm_out, norm_in, Wt0hi, Wt0lo, b0, norm_out,
        nullptr, nullptr, h1);

    // ---- Layers 2+3 (fused): t = relu(agg(h1)*ni @ W1 + b1)*no; tbf = t @ W2
    // tbf overwrites bfbuf (featbf dead after layer 1).
    fused_layer_kernel<false, true><<<fusedBlocks, 256, 0, stream>>>(
        h1, csr, row_start, nullptr, norm_in, Wt1hi, Wt1lo, b1, norm_out,
        Wt2hi, Wt2lo, bfbuf);

    // ---- final: out = agg(tbf)*ni + b2
    final_gather_kernel<<<gatherBlocks, 256, 0, stream>>>(
        bfbuf, csr, row_start, norm_in, b2, out);
}